// Round 1
// baseline (1418.378 us; speedup 1.0000x reference)
//
#include <hip/hip_runtime.h>
#include <math.h>

#define BB 512
#define TT 1024
#define KK 48

static constexpr float L2E = 1.4426950408889634f;   // log2(e)
static constexpr float LN2 = 0.6931471805599453f;   // ln(2)

__device__ __forceinline__ float wave_reduce_sum_f(float v) {
    #pragma unroll
    for (int m = 32; m >= 1; m >>= 1) v += __shfl_xor(v, m, 64);
    return v;
}
__device__ __forceinline__ int wave_reduce_sum_i(int v) {
    #pragma unroll
    for (int m = 32; m >= 1; m >>= 1) v += __shfl_xor(v, m, 64);
    return v;
}

__global__ __launch_bounds__(64) void crf_kernel(
    const float* __restrict__ emissions,   // (B, T, K)
    const int*   __restrict__ tags,        // (B, T)
    const void*  __restrict__ mask,        // (B, T) — dtype probed at runtime
    const float* __restrict__ transitions, // (K, K)
    const float* __restrict__ start_t,     // (K,)
    const float* __restrict__ end_t,       // (K,)
    float*       __restrict__ out)         // (B,)
{
    const int b    = blockIdx.x;
    const int lane = threadIdx.x;
    const float* em = emissions + (size_t)b * TT * KK;
    const int*   tg = tags      + (size_t)b * TT;

    // ---- determine mask storage layout & compute length L ----
    // mask[0][0] is always true (lengths >= T/2), so first word discriminates:
    //   int32 layout -> 1 ; float32 layout -> 0x3f800000 ; byte layout -> e.g. 0x01010101
    const unsigned w0 = *((const unsigned*)mask);
    int c = 0;
    if (w0 == 1u) {
        const int* mp = (const int*)mask + (size_t)b * TT;
        for (int t = lane; t < TT; t += 64) c += (mp[t] != 0);
    } else if (w0 == 0x3f800000u) {
        const float* mp = (const float*)mask + (size_t)b * TT;
        for (int t = lane; t < TT; t += 64) c += (mp[t] != 0.0f);
    } else {
        const unsigned char* mp = (const unsigned char*)mask + (size_t)b * TT;
        for (int t = lane; t < TT; t += 64) c += (mp[t] != 0);
    }
    const int L = wave_reduce_sum_i(c);   // prefix mask -> popcount == length

    // ---- numerator (path score) ----
    // score = start[tag0] + em[0,tag0] + sum_{t=1}^{L-1} (em[t,tag_t] + trans[tag_{t-1}, tag_t]) + end[tag_{L-1}]
    float sc = 0.0f;
    for (int t = lane; t < TT; t += 64) {
        if (t < L) {
            const int tagt = tg[t];
            float term = em[(size_t)t * KK + tagt];
            term += (t == 0) ? start_t[tagt] : transitions[tg[t - 1] * KK + tagt];
            sc += term;
        }
    }
    sc = wave_reduce_sum_f(sc);
    const float score = sc + end_t[tg[L - 1]];

    // ---- denominator: forward recursion in base-2 scaled log domain ----
    // A (scaled) = alpha * log2(e).  Recursion (NOTE reference uses trans[next, prev] here):
    //   A_new[j] = log2( sum_i 2^(A[i] + Ts[j][i]) ) + e[t,j]*L2E
    // Keep A relative to a running offset CS (anchored at lane 0's value).
    const int j   = lane;
    const int row = (j < KK) ? j : 0;
    float Ts[KK];
    #pragma unroll
    for (int i = 0; i < KK; ++i) Ts[i] = transitions[row * KK + i] * L2E;

    float A = (j < KK) ? (start_t[j] + em[j]) * L2E : -INFINITY;
    const float a0 = __shfl(A, 0, 64);
    float CS = a0;
    A -= a0;           // lane >= 48: stays -inf, never written to LDS

    __shared__ __align__(16) float sm[KK];

    for (int t = 1; t < L; ++t) {
        // prefetch this step's emission early (consumed after the inner loop)
        const float e = (j < KK) ? em[(size_t)t * KK + j] : 0.0f;

        if (j < KK) sm[j] = A;
        __syncthreads();

        float s = 0.0f;
        const float4* sm4 = (const float4*)sm;
        #pragma unroll
        for (int i = 0; i < KK / 4; ++i) {
            const float4 a4 = sm4[i];           // broadcast read, conflict-free
            s += exp2f(a4.x + Ts[4 * i + 0]);
            s += exp2f(a4.y + Ts[4 * i + 1]);
            s += exp2f(a4.z + Ts[4 * i + 2]);
            s += exp2f(a4.w + Ts[4 * i + 3]);
        }
        const float v  = log2f(s) + e * L2E;    // scaled new alpha before offset
        const float v0 = __shfl(v, 0, 64);
        A  = v - v0;
        CS += v0;
        __syncthreads();                         // protect sm before next write
    }

    // ---- log_den = ln2 * ( CS + log2( sum_j 2^(A[j] + end[j]*L2E) ) ) ----
    const float contrib = (j < KK) ? exp2f(A + end_t[j] * L2E) : 0.0f;
    const float ssum    = wave_reduce_sum_f(contrib);
    const float log_den = LN2 * (CS + log2f(ssum));

    if (lane == 0) out[b] = score - log_den;
}

extern "C" void kernel_launch(void* const* d_in, const int* in_sizes, int n_in,
                              void* d_out, int out_size, void* d_ws, size_t ws_size,
                              hipStream_t stream) {
    const float* emissions   = (const float*)d_in[0];
    const int*   tags        = (const int*)  d_in[1];
    const void*  mask        = (const void*) d_in[2];
    const float* transitions = (const float*)d_in[3];
    const float* start_t     = (const float*)d_in[4];
    const float* end_t       = (const float*)d_in[5];
    float* out = (float*)d_out;

    crf_kernel<<<BB, 64, 0, stream>>>(emissions, tags, mask, transitions,
                                      start_t, end_t, out);
}

// Round 2
// 614.673 us; speedup vs baseline: 2.3075x; 2.3075x over previous
//
#include <hip/hip_runtime.h>
#include <math.h>

#define BB 512
#define TT 1024
#define KK 48

static constexpr float L2E = 1.4426950408889634f;   // log2(e)
static constexpr float LN2 = 0.6931471805599453f;   // ln(2)

__device__ __forceinline__ float wave_reduce_sum_f(float v) {
    #pragma unroll
    for (int m = 32; m >= 1; m >>= 1) v += __shfl_xor(v, m, 64);
    return v;
}
__device__ __forceinline__ int wave_reduce_sum_i(int v) {
    #pragma unroll
    for (int m = 32; m >= 1; m >>= 1) v += __shfl_xor(v, m, 64);
    return v;
}

__global__ __launch_bounds__(64) void crf_kernel(
    const float* __restrict__ emissions,   // (B, T, K)
    const int*   __restrict__ tags,        // (B, T)
    const void*  __restrict__ mask,        // (B, T) — dtype probed at runtime
    const float* __restrict__ transitions, // (K, K)
    const float* __restrict__ start_t,     // (K,)
    const float* __restrict__ end_t,       // (K,)
    float*       __restrict__ out)         // (B,)
{
    const int b    = blockIdx.x;
    const int lane = threadIdx.x;
    const float* em = emissions + (size_t)b * TT * KK;
    const int*   tg = tags      + (size_t)b * TT;

    // ---- mask layout probe (same as round 1, which passed) ----
    const unsigned w0 = *((const unsigned*)mask);
    int c = 0;
    if (w0 == 1u) {
        const int* mp = (const int*)mask + (size_t)b * TT;
        for (int t = lane; t < TT; t += 64) c += (mp[t] != 0);
    } else if (w0 == 0x3f800000u) {
        const float* mp = (const float*)mask + (size_t)b * TT;
        for (int t = lane; t < TT; t += 64) c += (mp[t] != 0.0f);
    } else {
        const unsigned char* mp = (const unsigned char*)mask + (size_t)b * TT;
        for (int t = lane; t < TT; t += 64) c += (mp[t] != 0);
    }
    const int L = wave_reduce_sum_i(c);   // prefix mask -> popcount == length

    // ---- numerator (path score) ----
    float sc = 0.0f;
    for (int t = lane; t < TT; t += 64) {
        if (t < L) {
            const int tagt = tg[t];
            float term = em[(size_t)t * KK + tagt];
            term += (t == 0) ? start_t[tagt] : transitions[tg[t - 1] * KK + tagt];
            sc += term;
        }
    }
    sc = wave_reduce_sum_f(sc);
    const float score = sc + end_t[tg[L - 1]];

    // ---- denominator: SCALED LINEAR-SPACE forward algorithm ----
    // p_next[j] = (sum_i M[j][i] * p[i]) * exp(e_t[j]) / z_t,  CS += log2(z_t)
    // where M[j][i] = exp(transitions[j][i])  (j = next state, per reference's
    // lse over axis=2), constant across all steps -> held in 48 VGPRs.
    const int j   = lane;
    const int row = (j < KK) ? j : 0;
    float M[KK];
    #pragma unroll
    for (int i = 0; i < KK; ++i) M[i] = exp2f(transitions[row * KK + i] * L2E);

    // init: p[j] = 2^((start+em0)*L2E - C0), CS = C0 (lane-0 anchor, log2 units)
    const float A0 = (j < KK) ? (start_t[j] + em[j]) * L2E : 0.0f;
    const float C0 = __shfl(A0, 0, 64);
    float p  = (j < KK) ? exp2f(A0 - C0) : 0.0f;
    float CS = C0;

    // emission prefetch, depth 2 (hide HBM/L2 latency off the serial chain)
    float e2 = (j < KK) ? em[(size_t)1 * KK + j] : 0.0f;   // raw e[1]
    float E  = exp2f(e2 * L2E);                            // E for t=1
    e2 = (j < KK) ? em[(size_t)2 * KK + j] : 0.0f;         // raw e[2]

    for (int t = 1; t < L; ++t) {
        // issue load for e[t+2] immediately (consumed 2 iterations later)
        float e3 = 0.0f;
        const int tp = t + 2;
        if (j < KK && tp < TT) e3 = em[(size_t)tp * KK + j];

        // s[j] = sum_i M[j][i] * p[i]   — bpermute broadcast, no barriers
        float s0 = 0.f, s1 = 0.f, s2 = 0.f, s3 = 0.f;
        #pragma unroll
        for (int i = 0; i < KK; i += 4) {
            s0 = fmaf(M[i + 0], __shfl(p, i + 0, 64), s0);
            s1 = fmaf(M[i + 1], __shfl(p, i + 1, 64), s1);
            s2 = fmaf(M[i + 2], __shfl(p, i + 2, 64), s2);
            s3 = fmaf(M[i + 3], __shfl(p, i + 3, 64), s3);
        }
        const float u = ((s0 + s1) + (s2 + s3)) * E;

        // next step's emission factor — off the critical chain
        E  = exp2f(e2 * L2E);
        e2 = e3;

        // renormalize by lane-0 value (wave-uniform), track log
        const float z = __shfl(u, 0, 64);
        p   = u * __builtin_amdgcn_rcpf(z);
        CS += log2f(z);
    }

    // log_den = ln2 * (CS + log2(sum_j p[j] * exp(end[j])))
    const float contrib = (j < KK) ? p * exp2f(end_t[j] * L2E) : 0.0f;
    const float ssum    = wave_reduce_sum_f(contrib);
    const float log_den = LN2 * (CS + log2f(ssum));

    if (lane == 0) out[b] = score - log_den;
}

extern "C" void kernel_launch(void* const* d_in, const int* in_sizes, int n_in,
                              void* d_out, int out_size, void* d_ws, size_t ws_size,
                              hipStream_t stream) {
    const float* emissions   = (const float*)d_in[0];
    const int*   tags        = (const int*)  d_in[1];
    const void*  mask        = (const void*) d_in[2];
    const float* transitions = (const float*)d_in[3];
    const float* start_t     = (const float*)d_in[4];
    const float* end_t       = (const float*)d_in[5];
    float* out = (float*)d_out;

    crf_kernel<<<BB, 64, 0, stream>>>(emissions, tags, mask, transitions,
                                      start_t, end_t, out);
}

// Round 3
// 400.760 us; speedup vs baseline: 3.5392x; 1.5338x over previous
//
#include <hip/hip_runtime.h>
#include <math.h>

#define BB 512
#define TT 1024
#define KK 48
#define PF 8   // emission prefetch depth (register ring)

static constexpr float L2E = 1.4426950408889634f;   // log2(e)
static constexpr float LN2 = 0.6931471805599453f;   // ln(2)

__device__ __forceinline__ float wave_reduce_sum_f(float v) {
    #pragma unroll
    for (int m = 32; m >= 1; m >>= 1) v += __shfl_xor(v, m, 64);
    return v;
}
__device__ __forceinline__ int wave_reduce_sum_i(int v) {
    #pragma unroll
    for (int m = 32; m >= 1; m >>= 1) v += __shfl_xor(v, m, 64);
    return v;
}

__global__ __launch_bounds__(64) void crf_kernel(
    const float* __restrict__ emissions,   // (B, T, K)
    const int*   __restrict__ tags,        // (B, T)
    const void*  __restrict__ mask,        // (B, T) — dtype probed at runtime
    const float* __restrict__ transitions, // (K, K)
    const float* __restrict__ start_t,     // (K,)
    const float* __restrict__ end_t,       // (K,)
    float*       __restrict__ out)         // (B,)
{
    const int b    = blockIdx.x;
    const int lane = threadIdx.x;
    const float* em = emissions + (size_t)b * TT * KK;
    const int*   tg = tags      + (size_t)b * TT;

    // ---- mask layout probe (unchanged from passing rounds) ----
    const unsigned w0 = *((const unsigned*)mask);
    int c = 0;
    if (w0 == 1u) {
        const int* mp = (const int*)mask + (size_t)b * TT;
        for (int t = lane; t < TT; t += 64) c += (mp[t] != 0);
    } else if (w0 == 0x3f800000u) {
        const float* mp = (const float*)mask + (size_t)b * TT;
        for (int t = lane; t < TT; t += 64) c += (mp[t] != 0.0f);
    } else {
        const unsigned char* mp = (const unsigned char*)mask + (size_t)b * TT;
        for (int t = lane; t < TT; t += 64) c += (mp[t] != 0);
    }
    const int L = wave_reduce_sum_i(c);   // prefix mask -> popcount == length

    // ---- numerator (path score) ----
    float sc = 0.0f;
    for (int t = lane; t < TT; t += 64) {
        if (t < L) {
            const int tagt = tg[t];
            float term = em[(size_t)t * KK + tagt];
            term += (t == 0) ? start_t[tagt] : transitions[tg[t - 1] * KK + tagt];
            sc += term;
        }
    }
    sc = wave_reduce_sum_f(sc);
    const float score = sc + end_t[tg[L - 1]];

    // ---- denominator: scaled linear-space forward, deferred normalization ----
    // LDS holds UNNORMALIZED u_t; rz = rcp(u_t[0]) folded into the NEXT step's
    // scale, so rcp/shfl/log2 run concurrently with the read+FMA phase.
    //   u_t = (M · u_{t-1}) * E_t * rz_{t-1},  CS += log2(u_t[0])
    const int j  = lane;
    const int jj = (j < KK) ? j : 0;           // safe addressing for idle lanes
    float M[KK];
    #pragma unroll
    for (int i = 0; i < KK; ++i) M[i] = exp2f(transitions[jj * KK + i] * L2E);

    __shared__ __align__(16) float sm[KK];

    // init: u_0 = 2^(A0 - C0) (lane-0 anchor), rz_0 = 1, CS = C0
    const float A0 = (j < KK) ? (start_t[j] + em[j]) * L2E : 0.0f;
    const float C0 = __shfl(A0, 0, 64);
    float u  = (j < KK) ? exp2f(A0 - C0) : 0.0f;
    float rz = 1.0f;
    float CS = C0;
    if (j < KK) sm[j] = u;

    // emission register ring: cur[k] holds raw em[t+k][j] at loop top
    float cur[PF];
    #pragma unroll
    for (int k = 0; k < PF; ++k) {
        const int tt = (1 + k < TT) ? (1 + k) : (TT - 1);
        cur[k] = em[(size_t)tt * KK + jj];
    }

    int t = 1;
    for (; t + PF <= L; t += PF) {
        // prefetch next chunk (8 independent coalesced loads, ~2000cy of slack)
        float nxt[PF];
        #pragma unroll
        for (int k = 0; k < PF; ++k) {
            int tt = t + PF + k;
            tt = (tt < TT) ? tt : (TT - 1);
            nxt[k] = em[(size_t)tt * KK + jj];
        }
        #pragma unroll
        for (int k = 0; k < PF; ++k) {
            const float E = exp2f(cur[k] * L2E);          // off-chain
            // s[j] = sum_i M[j][i] * u[i] — 12 broadcast b128 reads, 8 accs
            const float4* sm4 = (const float4*)sm;
            float a0=0.f,a1=0.f,a2=0.f,a3=0.f,a4=0.f,a5=0.f,a6=0.f,a7=0.f;
            #pragma unroll
            for (int r = 0; r < 6; ++r) {
                const float4 x = sm4[2 * r];
                const float4 y = sm4[2 * r + 1];
                a0 = fmaf(M[8*r+0], x.x, a0); a1 = fmaf(M[8*r+1], x.y, a1);
                a2 = fmaf(M[8*r+2], x.z, a2); a3 = fmaf(M[8*r+3], x.w, a3);
                a4 = fmaf(M[8*r+4], y.x, a4); a5 = fmaf(M[8*r+5], y.y, a5);
                a6 = fmaf(M[8*r+6], y.z, a6); a7 = fmaf(M[8*r+7], y.w, a7);
            }
            const float s = (((a0+a1)+(a2+a3)) + ((a4+a5)+(a6+a7)));
            u = s * (E * rz);                              // E*rz precomputed off-chain
            if (j < KK) sm[j] = u;                         // feeds next step's reads
            // off-chain: normalization bookkeeping for NEXT step
            const float z = __shfl(u, 0, 64);
            rz  = __builtin_amdgcn_rcpf(z);
            CS += log2f(z);
        }
        #pragma unroll
        for (int k = 0; k < PF; ++k) cur[k] = nxt[k];
    }
    // epilogue: < PF remaining steps, cur[] already holds their emissions
    #pragma unroll
    for (int k = 0; k < PF; ++k) {
        if (t + k < L) {
            const float E = exp2f(cur[k] * L2E);
            const float4* sm4 = (const float4*)sm;
            float a0=0.f,a1=0.f,a2=0.f,a3=0.f,a4=0.f,a5=0.f,a6=0.f,a7=0.f;
            #pragma unroll
            for (int r = 0; r < 6; ++r) {
                const float4 x = sm4[2 * r];
                const float4 y = sm4[2 * r + 1];
                a0 = fmaf(M[8*r+0], x.x, a0); a1 = fmaf(M[8*r+1], x.y, a1);
                a2 = fmaf(M[8*r+2], x.z, a2); a3 = fmaf(M[8*r+3], x.w, a3);
                a4 = fmaf(M[8*r+4], y.x, a4); a5 = fmaf(M[8*r+5], y.y, a5);
                a6 = fmaf(M[8*r+6], y.z, a6); a7 = fmaf(M[8*r+7], y.w, a7);
            }
            const float s = (((a0+a1)+(a2+a3)) + ((a4+a5)+(a6+a7)));
            u = s * (E * rz);
            if (j < KK) sm[j] = u;
            const float z = __shfl(u, 0, 64);
            rz  = __builtin_amdgcn_rcpf(z);
            CS += log2f(z);
        }
    }

    // log_den = ln2 * (CS + log2(sum_j (u[j]*rz) * 2^(end[j]*L2E)))
    const float contrib = (j < KK) ? (u * rz) * exp2f(end_t[j] * L2E) : 0.0f;
    const float ssum    = wave_reduce_sum_f(contrib);
    const float log_den = LN2 * (CS + log2f(ssum));

    if (lane == 0) out[b] = score - log_den;
}

extern "C" void kernel_launch(void* const* d_in, const int* in_sizes, int n_in,
                              void* d_out, int out_size, void* d_ws, size_t ws_size,
                              hipStream_t stream) {
    const float* emissions   = (const float*)d_in[0];
    const int*   tags        = (const int*)  d_in[1];
    const void*  mask        = (const void*) d_in[2];
    const float* transitions = (const float*)d_in[3];
    const float* start_t     = (const float*)d_in[4];
    const float* end_t       = (const float*)d_in[5];
    float* out = (float*)d_out;

    crf_kernel<<<BB, 64, 0, stream>>>(emissions, tags, mask, transitions,
                                      start_t, end_t, out);
}

// Round 4
// 354.960 us; speedup vs baseline: 3.9959x; 1.1290x over previous
//
#include <hip/hip_runtime.h>
#include <math.h>

#define BB 512
#define TT 1024
#define KK 48
#define PF 8   // emission prefetch depth (register ring)

static constexpr float L2E = 1.4426950408889634f;   // log2(e)
static constexpr float LN2 = 0.6931471805599453f;   // ln(2)

__device__ __forceinline__ float wave_reduce_sum_f(float v) {
    #pragma unroll
    for (int m = 32; m >= 1; m >>= 1) v += __shfl_xor(v, m, 64);
    return v;
}
__device__ __forceinline__ int wave_reduce_sum_i(int v) {
    #pragma unroll
    for (int m = 32; m >= 1; m >>= 1) v += __shfl_xor(v, m, 64);
    return v;
}

// wave-uniform broadcast of lane i's value — VALU pipe (v_readlane), not DS
__device__ __forceinline__ float rlane(float v, int i) {
    return __uint_as_float(__builtin_amdgcn_readlane(__float_as_uint(v), i));
}

__global__ __launch_bounds__(64) void crf_kernel(
    const float* __restrict__ emissions,   // (B, T, K)
    const int*   __restrict__ tags,        // (B, T)
    const void*  __restrict__ mask,        // (B, T) — dtype probed at runtime
    const float* __restrict__ transitions, // (K, K)
    const float* __restrict__ start_t,     // (K,)
    const float* __restrict__ end_t,       // (K,)
    float*       __restrict__ out)         // (B,)
{
    const int b    = blockIdx.x;
    const int lane = threadIdx.x;
    const float* em = emissions + (size_t)b * TT * KK;
    const int*   tg = tags      + (size_t)b * TT;

    // ---- mask layout probe (unchanged from passing rounds) ----
    const unsigned w0 = *((const unsigned*)mask);
    int c = 0;
    if (w0 == 1u) {
        const int* mp = (const int*)mask + (size_t)b * TT;
        for (int t = lane; t < TT; t += 64) c += (mp[t] != 0);
    } else if (w0 == 0x3f800000u) {
        const float* mp = (const float*)mask + (size_t)b * TT;
        for (int t = lane; t < TT; t += 64) c += (mp[t] != 0.0f);
    } else {
        const unsigned char* mp = (const unsigned char*)mask + (size_t)b * TT;
        for (int t = lane; t < TT; t += 64) c += (mp[t] != 0);
    }
    const int L = wave_reduce_sum_i(c);   // prefix mask -> popcount == length

    // ---- numerator (path score) ----
    float sc = 0.0f;
    for (int t = lane; t < TT; t += 64) {
        if (t < L) {
            const int tagt = tg[t];
            float term = em[(size_t)t * KK + tagt];
            term += (t == 0) ? start_t[tagt] : transitions[tg[t - 1] * KK + tagt];
            sc += term;
        }
    }
    sc = wave_reduce_sum_f(sc);
    const float score = sc + end_t[tg[L - 1]];

    // ---- denominator: scaled linear-space forward ----
    // u_t = (M · u_{t-1}) * E_t * rz_{t-1},  CS += log2(z_t), z_t = u_t[0]
    // Broadcast of u[i] now via v_readlane (VALU, uniform unrolled index) —
    // no LDS, no DS pipe on the chain at all.
    const int j  = lane;
    const int jj = (j < KK) ? j : 0;
    float M[KK];
    #pragma unroll
    for (int i = 0; i < KK; ++i) M[i] = exp2f(transitions[jj * KK + i] * L2E);

    const float A0 = (j < KK) ? (start_t[j] + em[j]) * L2E : 0.0f;
    const float C0 = rlane(A0, 0);
    float u  = exp2f(A0 - C0);        // lanes >= 48 hold garbage, never read
    float rz = 1.0f;
    float CS = C0;

    // emission register ring: cur[k] holds raw em[t+k][j] at loop top
    float cur[PF];
    #pragma unroll
    for (int k = 0; k < PF; ++k) {
        const int tt = (1 + k < TT) ? (1 + k) : (TT - 1);
        cur[k] = em[(size_t)tt * KK + jj];
    }

    int t = 1;
    for (; t + PF <= L; t += PF) {
        float nxt[PF];
        #pragma unroll
        for (int k = 0; k < PF; ++k) {
            int tt = t + PF + k;
            tt = (tt < TT) ? tt : (TT - 1);
            nxt[k] = em[(size_t)tt * KK + jj];
        }
        #pragma unroll
        for (int k = 0; k < PF; ++k) {
            const float E = exp2f(cur[k] * L2E);          // off-chain
            float a0=0.f,a1=0.f,a2=0.f,a3=0.f,a4=0.f,a5=0.f,a6=0.f,a7=0.f;
            #pragma unroll
            for (int r = 0; r < 6; ++r) {                  // 48 readlane + 48 FMA
                a0 = fmaf(M[8*r+0], rlane(u, 8*r+0), a0);
                a1 = fmaf(M[8*r+1], rlane(u, 8*r+1), a1);
                a2 = fmaf(M[8*r+2], rlane(u, 8*r+2), a2);
                a3 = fmaf(M[8*r+3], rlane(u, 8*r+3), a3);
                a4 = fmaf(M[8*r+4], rlane(u, 8*r+4), a4);
                a5 = fmaf(M[8*r+5], rlane(u, 8*r+5), a5);
                a6 = fmaf(M[8*r+6], rlane(u, 8*r+6), a6);
                a7 = fmaf(M[8*r+7], rlane(u, 8*r+7), a7);
            }
            const float s = (((a0+a1)+(a2+a3)) + ((a4+a5)+(a6+a7)));
            u = s * (E * rz);                              // E*rz ready off-chain
            // deferred normalization bookkeeping (consumed next step, off-chain)
            const float z = rlane(u, 0);
            rz  = __builtin_amdgcn_rcpf(z);
            CS += log2f(z);
        }
        #pragma unroll
        for (int k = 0; k < PF; ++k) cur[k] = nxt[k];
    }
    // epilogue: < PF remaining steps, cur[] already holds their emissions
    #pragma unroll
    for (int k = 0; k < PF; ++k) {
        if (t + k < L) {
            const float E = exp2f(cur[k] * L2E);
            float a0=0.f,a1=0.f,a2=0.f,a3=0.f,a4=0.f,a5=0.f,a6=0.f,a7=0.f;
            #pragma unroll
            for (int r = 0; r < 6; ++r) {
                a0 = fmaf(M[8*r+0], rlane(u, 8*r+0), a0);
                a1 = fmaf(M[8*r+1], rlane(u, 8*r+1), a1);
                a2 = fmaf(M[8*r+2], rlane(u, 8*r+2), a2);
                a3 = fmaf(M[8*r+3], rlane(u, 8*r+3), a3);
                a4 = fmaf(M[8*r+4], rlane(u, 8*r+4), a4);
                a5 = fmaf(M[8*r+5], rlane(u, 8*r+5), a5);
                a6 = fmaf(M[8*r+6], rlane(u, 8*r+6), a6);
                a7 = fmaf(M[8*r+7], rlane(u, 8*r+7), a7);
            }
            const float s = (((a0+a1)+(a2+a3)) + ((a4+a5)+(a6+a7)));
            u = s * (E * rz);
            const float z = rlane(u, 0);
            rz  = __builtin_amdgcn_rcpf(z);
            CS += log2f(z);
        }
    }

    // log_den = ln2 * (CS + log2(sum_j (u[j]*rz) * 2^(end[j]*L2E)))
    const float contrib = (j < KK) ? (u * rz) * exp2f(end_t[j] * L2E) : 0.0f;
    const float ssum    = wave_reduce_sum_f(contrib);
    const float log_den = LN2 * (CS + log2f(ssum));

    if (lane == 0) out[b] = score - log_den;
}

extern "C" void kernel_launch(void* const* d_in, const int* in_sizes, int n_in,
                              void* d_out, int out_size, void* d_ws, size_t ws_size,
                              hipStream_t stream) {
    const float* emissions   = (const float*)d_in[0];
    const int*   tags        = (const int*)  d_in[1];
    const void*  mask        = (const void*) d_in[2];
    const float* transitions = (const float*)d_in[3];
    const float* start_t     = (const float*)d_in[4];
    const float* end_t       = (const float*)d_in[5];
    float* out = (float*)d_out;

    crf_kernel<<<BB, 64, 0, stream>>>(emissions, tags, mask, transitions,
                                      start_t, end_t, out);
}